// Round 3
// baseline (592.776 us; speedup 1.0000x reference)
//
#include <hip/hip_runtime.h>

typedef float v2 __attribute__((ext_vector_type(2)));
typedef float v4 __attribute__((ext_vector_type(4)));

#define B_TOT 2048
#define T_STEPS 512
// D = 8, M = 2

// out layout (flat floats):
//   means: [B,T,8]    at 0
//   covs : [B,T,8,8]  at 8388608
//   Rs   : [B,T,2,2]  at 75497472
//   Hs   : [B,T,2,8]  at 79691776
#define OFF_COVS 8388608
#define OFF_RS   75497472
#define OFF_HS   79691776

// chain stride (floats) in comm LDS: 104 % 32 == 8 -> every scatter/gather
// instruction lands 2-way max on the 32 banks (2-way is free, m136).
// region per chain: W[d][f] at d*8+f (0..63), hp0 at 64+j, hp1 at 72+j.
#define CSTR 104

static __device__ __forceinline__ v2 sp(float s) { v2 r; r.x = s; r.y = s; return r; }

__launch_bounds__(64, 1)
__global__ void kf_kernel(const float* __restrict__ input,
                          const float* __restrict__ mean0,
                          const float* __restrict__ cov0,
                          const float* __restrict__ Fm,
                          const float* __restrict__ Hm,
                          const float* __restrict__ Qm,
                          const float* __restrict__ Rm,
                          float* __restrict__ out)
{
    __shared__ float xs[8 * 1024];      // staged input: 8 chains x (T*M)
    __shared__ float comm[8 * CSTR];    // single comm region (W + hp), conflict-free

    const int lane = threadIdx.x;       // 0..63; block = 1 wave, no __syncthreads needed
    const int g = lane >> 3;            // chain within block
    const int j = lane & 7;             // row index
    const int b0 = blockIdx.x * 8;
    const int b = b0 + g;

    // ---- stage input (8 chains x 1024 floats, contiguous) ----
    {
        const v4* src = (const v4*)(input + (size_t)b0 * 1024);
        v4* dst = (v4*)xs;
        #pragma unroll
        for (int i = 0; i < 32; ++i)
            dst[i * 64 + lane] = src[i * 64 + lane];
    }

    // ---- replicated constants ----
    // Fcol2[f][d2] = { F[2*d2, f], F[2*d2+1, f] } : y[d2] += Fcol2[f][d2]*x[f] gives y = F*x
    v2 Fcol2[8][4];
    #pragma unroll
    for (int f = 0; f < 8; ++f)
        #pragma unroll
        for (int d2 = 0; d2 < 4; ++d2) {
            v2 t; t.x = Fm[(2 * d2) * 8 + f]; t.y = Fm[(2 * d2 + 1) * 8 + f];
            Fcol2[f][d2] = t;
        }
    v2 Frowj[4];                        // row j of F (for d0,d1 dots only)
    #pragma unroll
    for (int d2 = 0; d2 < 4; ++d2) {
        v2 t; t.x = Fm[j * 8 + 2 * d2]; t.y = Fm[j * 8 + 2 * d2 + 1];
        Frowj[d2] = t;
    }
    v2 Hrow2[2][4];
    #pragma unroll
    for (int m = 0; m < 2; ++m)
        #pragma unroll
        for (int d2 = 0; d2 < 4; ++d2) {
            v2 t; t.x = Hm[m * 8 + 2 * d2]; t.y = Hm[m * 8 + 2 * d2 + 1];
            Hrow2[m][d2] = t;
        }
    v2 Qrow2[4];
    #pragma unroll
    for (int e2 = 0; e2 < 4; ++e2) {
        v2 t; t.x = Qm[j * 8 + 2 * e2]; t.y = Qm[j * 8 + 2 * e2 + 1];
        Qrow2[e2] = t;
    }
    const float r00 = Rm[0], r01 = Rm[1], r10 = Rm[2], r11 = Rm[3];
    const float Rval = (j == 0) ? r00 : (j == 1) ? r01 : (j == 2) ? r10 : r11;
    v2 Hflat; Hflat.x = Hm[2 * j]; Hflat.y = Hm[2 * j + 1];

    // ---- state: row j of P (symmetric: row == column) + FULL mean vector ----
    v2 P2[4];
    {
        const v4* c4 = (const v4*)(cov0 + (size_t)b * 64 + j * 8);
        v4 a = c4[0], bb = c4[1];
        P2[0].x = a.x;  P2[0].y = a.y;  P2[1].x = a.z;  P2[1].y = a.w;
        P2[2].x = bb.x; P2[2].y = bb.y; P2[3].x = bb.z; P2[3].y = bb.w;
    }
    v2 mn[4];                           // full mean (redundant in all 8 lanes) -> no mean comm
    {
        const v4* m4 = (const v4*)(mean0 + (size_t)b * 8);
        v4 a = m4[0], bb = m4[1];
        mn[0].x = a.x;  mn[0].y = a.y;  mn[1].x = a.z;  mn[1].y = a.w;
        mn[2].x = bb.x; mn[2].y = bb.y; mn[3].x = bb.z; mn[3].y = bb.w;
    }

    // ---- output pointers ----
    float* means_p = out + (size_t)b * T_STEPS * 8;                 // j==0 stores whole vector
    float* covs_p  = out + OFF_COVS + (size_t)b * T_STEPS * 64 + j * 8;
    float* Rs_p    = out + OFF_RS + (size_t)b * T_STEPS * 4 + j;    // j < 4 only
    float* Hs_p    = out + OFF_HS + (size_t)b * T_STEPS * 16 + 2 * j;
    const v2* xv   = (const v2*)(xs + g * 1024);
    float* cm      = comm + g * CSTR;

    v2 xcur = xv[0];

    for (int t = 0; t < T_STEPS; ++t) {
        // ===== phase A: everything scatterable from P (state) =====
        // hp[m] = HP[m,j] = H_row_m . P_row_j  (local via symmetry)
        v2 a0 = {0.f, 0.f}, a1 = {0.f, 0.f};
        #pragma unroll
        for (int d2 = 0; d2 < 4; ++d2) { a0 += Hrow2[0][d2] * P2[d2]; a1 += Hrow2[1][d2] * P2[d2]; }
        const float hp0 = a0.x + a0.y;
        const float hp1 = a1.x + a1.y;

        // W = F*P, column j (local: col j of P == row j)
        v2 W2[4] = {{0.f,0.f},{0.f,0.f},{0.f,0.f},{0.f,0.f}};
        #pragma unroll
        for (int f = 0; f < 8; ++f) {
            const float pf = (f & 1) ? P2[f >> 1].y : P2[f >> 1].x;
            const v2 c = sp(pf);
            #pragma unroll
            for (int d2 = 0; d2 < 4; ++d2) W2[d2] += Fcol2[f][d2] * c;
        }

        // single scatter phase: W column (transposed store) + hp
        #pragma unroll
        for (int d = 0; d < 8; ++d) {
            const float wd = (d & 1) ? W2[d >> 1].y : W2[d >> 1].x;
            cm[d * 8 + j] = wd;         // bank = (104g + 8d + j)%32 -> 2-way max
        }
        cm[64 + j] = hp0;
        cm[72 + j] = hp1;

        // ===== phase B: independent work (fills the DS round-trip) =====
        if (j == 0) {                   // whole mean vector from registers
            v4 mva, mvb;
            mva.x = mn[0].x; mva.y = mn[0].y; mva.z = mn[1].x; mva.w = mn[1].y;
            mvb.x = mn[2].x; mvb.y = mn[2].y; mvb.z = mn[3].x; mvb.w = mn[3].y;
            ((v4*)means_p)[0] = mva;
            ((v4*)means_p)[1] = mvb;
        }
        {
            v4 cva, cvb;
            cva.x = P2[0].x; cva.y = P2[0].y; cva.z = P2[1].x; cva.w = P2[1].y;
            cvb.x = P2[2].x; cvb.y = P2[2].y; cvb.z = P2[3].x; cvb.w = P2[3].y;
            ((v4*)covs_p)[0] = cva;
            ((v4*)covs_p)[1] = cvb;
        }
        if (j < 4) Rs_p[0] = Rval;
        *((v2*)Hs_p) = Hflat;
        means_p += 8; covs_p += 64; Rs_p += 4; Hs_p += 16;

        const v2 xnext = xv[(t + 1) & (T_STEPS - 1)];

        // hm = H . mn  (local, independent of gather)
        v2 t0 = {0.f, 0.f}, t1 = {0.f, 0.f};
        #pragma unroll
        for (int d2 = 0; d2 < 4; ++d2) { t0 += Hrow2[0][d2] * mn[d2]; t1 += Hrow2[1][d2] * mn[d2]; }
        const float hm0 = t0.x + t0.y;
        const float hm1 = t1.x + t1.y;

        // ===== phase C: gathers (contiguous, conflict-audited) =====
        v2 hpa0[4], hpa1[4], Wr[4];
        {
            const v4* hp4 = (const v4*)(cm + 64);     // 16B aligned (104g+64)
            v4 ha = hp4[0], hb = hp4[1], hc = hp4[2], hd = hp4[3];
            hpa0[0].x = ha.x; hpa0[0].y = ha.y; hpa0[1].x = ha.z; hpa0[1].y = ha.w;
            hpa0[2].x = hb.x; hpa0[2].y = hb.y; hpa0[3].x = hb.z; hpa0[3].y = hb.w;
            hpa1[0].x = hc.x; hpa1[0].y = hc.y; hpa1[1].x = hc.z; hpa1[1].y = hc.w;
            hpa1[2].x = hd.x; hpa1[2].y = hd.y; hpa1[3].x = hd.z; hpa1[3].y = hd.w;
            const v4* w4 = (const v4*)(cm + j * 8);   // W row j, 32B contiguous
            v4 wa = w4[0], wb = w4[1];
            Wr[0].x = wa.x; Wr[0].y = wa.y; Wr[1].x = wa.z; Wr[1].y = wa.w;
            Wr[2].x = wb.x; Wr[2].y = wb.y; Wr[3].x = wb.z; Wr[3].y = wb.w;
        }

        // ===== S = HP H^T + R (2x2), closed-form inverse =====
        v2 s00v = {0.f, 0.f}, s01v = {0.f, 0.f}, s11v = {0.f, 0.f};
        #pragma unroll
        for (int f2 = 0; f2 < 4; ++f2) {
            s00v += hpa0[f2] * Hrow2[0][f2];
            s01v += hpa0[f2] * Hrow2[1][f2];
            s11v += hpa1[f2] * Hrow2[1][f2];
        }
        const float s00 = s00v.x + s00v.y + r00;
        const float s01 = s01v.x + s01v.y + r01;
        const float s11 = s11v.x + s11v.y + r11;
        const float det = s00 * s11 - s01 * s01;
        const float idet = __builtin_amdgcn_rcpf(det);
        const float i00 = s11 * idet, i01 = -s01 * idet, i11 = s00 * idet;

        // ===== mean: mean_u = mn + (iS*rs).hpa ; mn <- F*mean_u  (all local) =====
        const float rs0 = xcur.x - hm0;
        const float rs1 = xcur.y - hm1;
        const float aa0 = i00 * rs0 + i01 * rs1;
        const float aa1 = i01 * rs0 + i11 * rs1;
        v2 mu[4];
        {
            const v2 av0 = sp(aa0), av1 = sp(aa1);
            #pragma unroll
            for (int d2 = 0; d2 < 4; ++d2) mu[d2] = mn[d2] + av0 * hpa0[d2] + av1 * hpa1[d2];
        }
        {
            v2 nm[4] = {{0.f,0.f},{0.f,0.f},{0.f,0.f},{0.f,0.f}};
            #pragma unroll
            for (int e = 0; e < 8; ++e) {
                const float me = (e & 1) ? mu[e >> 1].y : mu[e >> 1].x;
                const v2 c = sp(me);
                #pragma unroll
                for (int d2 = 0; d2 < 4; ++d2) nm[d2] += Fcol2[e][d2] * c;
            }
            mn[0] = nm[0]; mn[1] = nm[1]; mn[2] = nm[2]; mn[3] = nm[3];
        }

        // ===== cov: P_next row j = F*(W_row_j - z) + Q,
        //        z = c0*hpa0 + c1*hpa1, c_m = iS[m,:]·(Frowj·hpa0, Frowj·hpa1) =====
        v2 dd0 = {0.f, 0.f}, dd1 = {0.f, 0.f};
        #pragma unroll
        for (int f2 = 0; f2 < 4; ++f2) { dd0 += Frowj[f2] * hpa0[f2]; dd1 += Frowj[f2] * hpa1[f2]; }
        const float d0 = dd0.x + dd0.y;
        const float d1 = dd1.x + dd1.y;
        const float c0 = i00 * d0 + i01 * d1;
        const float c1 = i01 * d0 + i11 * d1;
        v2 Wt[4];
        {
            const v2 c0v = sp(c0), c1v = sp(c1);
            #pragma unroll
            for (int f2 = 0; f2 < 4; ++f2) Wt[f2] = Wr[f2] - c0v * hpa0[f2] - c1v * hpa1[f2];
        }
        {
            v2 Pn[4] = {Qrow2[0], Qrow2[1], Qrow2[2], Qrow2[3]};
            #pragma unroll
            for (int f = 0; f < 8; ++f) {
                const float wtf = (f & 1) ? Wt[f >> 1].y : Wt[f >> 1].x;
                const v2 c = sp(wtf);
                #pragma unroll
                for (int e2 = 0; e2 < 4; ++e2) Pn[e2] += Fcol2[f][e2] * c;
            }
            P2[0] = Pn[0]; P2[1] = Pn[1]; P2[2] = Pn[2]; P2[3] = Pn[3];
        }

        xcur = xnext;
    }
}

extern "C" void kernel_launch(void* const* d_in, const int* in_sizes, int n_in,
                              void* d_out, int out_size, void* d_ws, size_t ws_size,
                              hipStream_t stream) {
    const float* input = (const float*)d_in[0];
    const float* mean0 = (const float*)d_in[1];
    const float* cov0  = (const float*)d_in[2];
    const float* F     = (const float*)d_in[3];
    const float* H     = (const float*)d_in[4];
    const float* Q     = (const float*)d_in[5];
    const float* R     = (const float*)d_in[6];
    float* out = (float*)d_out;

    hipLaunchKernelGGL(kf_kernel, dim3(B_TOT / 8), dim3(64), 0, stream,
                       input, mean0, cov0, F, H, Q, R, out);
}